// Round 6
// baseline (88.305 us; speedup 1.0000x reference)
//
#include <hip/hip_runtime.h>
#include <math.h>

#define B 64
#define S 300
#define R 100
#define F 10
#define RF (R * F)
#define K 16                    // lanes per tile
#define JMAX 7                  // reads per lane: r = l + 16j, j<7 (j=6 only l<4)
#define NTILE (B * S)           // 19200
#define NWAVE (NTILE / 4)       // 4 tiles per wave -> 4800 waves
#define NBLK (NWAVE / 4)        // 1200 blocks x 256 threads

__device__ __forceinline__ float elu1(float x) {
    return fmaxf(x, __expf(fminf(x, 0.f)) - 1.f);
}
// sum across the 16-lane group (xor masks 1,2,4,8 stay inside the group)
__device__ __forceinline__ float gsum(float v) {
#pragma unroll
    for (int m = 1; m < 16; m <<= 1) v += __shfl_xor(v, m, 64);
    return v;
}
__device__ __forceinline__ unsigned int fkey(float f) {
    unsigned int bits = __float_as_uint(f);
    return (bits & 0x80000000u) ? ~bits : (bits | 0x80000000u);
}

__global__ __launch_bounds__(256) void alt_pred_k1(
    const float* __restrict__ x,
    const float* __restrict__ l1_w, const float* __restrict__ l1_b,
    const float* __restrict__ l2_w, const float* __restrict__ l2_b,
    const float* __restrict__ l3_w, const float* __restrict__ l3_b,
    const float* __restrict__ fc1_w, const float* __restrict__ fc1_b,
    const float* __restrict__ fc2_w, const float* __restrict__ fc2_b,
    const float* __restrict__ fc3_w, const float* __restrict__ fc3_b,
    unsigned int* __restrict__ wsmax)
{
    const int tid = threadIdx.x;
    const int l = tid & (K - 1);                     // lane within tile group
    const int gt = (blockIdx.x * 256 + tid) >> 4;    // global tile = b*S + s
    const int b = gt / S;
    const float* xt = x + (size_t)gt * RF;

    // ---- load all owned reads' features once; stash in registers ----
    float f[JMAX][F];
    float msk[JMAX];
#pragma unroll
    for (int j = 0; j < JMAX; ++j) {
        const int r = l + K * j;
        const bool v = (r < R);
        msk[j] = v ? 1.f : 0.f;
        const float2* p = (const float2*)(xt + (v ? r : l) * F);
#pragma unroll
        for (int i = 0; i < 5; ++i) {
            float2 u = p[i];
            f[j][2 * i] = u.x; f[j][2 * i + 1] = u.y;
        }
    }
    // read-0 feats (tile base, 16B-aligned)
    const float4 x0 = *(const float4*)xt;

    // rdot per read
    float rdot[JMAX];
#pragma unroll
    for (int j = 0; j < JMAX; ++j)
        rdot[j] = fmaf(f[j][0], x0.x, fmaf(f[j][1], x0.y,
                  fmaf(f[j][2], x0.z, f[j][3] * x0.w)));

    // ---- bm: mean of feat[0:4] over 100 reads ----
    float bm[4];
#pragma unroll
    for (int k = 0; k < 4; ++k) {
        float s = 0.f;
#pragma unroll
        for (int j = 0; j < JMAX; ++j) s = fmaf(f[j][k], msk[j], s);
        bm[k] = gsum(s) * (1.f / R);
    }

    // ---- phase B: l1/l2/l3 per read, accumulate ym ----
    float pre1[5];
#pragma unroll
    for (int o = 0; o < 5; ++o) {
        float a = l1_b[o];
#pragma unroll
        for (int k = 0; k < 4; ++k) a = fmaf(bm[k], l1_w[o * 15 + k], a);
        pre1[o] = a;
    }
    float ymacc[5] = {0.f, 0.f, 0.f, 0.f, 0.f};
#pragma unroll
    for (int j = 0; j < JMAX; ++j) {
        float y1[5];
#pragma unroll
        for (int o = 0; o < 5; ++o) {
            float a = fmaf(rdot[j], l1_w[o * 15 + 4], pre1[o]);
#pragma unroll
            for (int k = 0; k < F; ++k) a = fmaf(f[j][k], l1_w[o * 15 + 5 + k], a);
            y1[o] = elu1(a);
        }
        float y2[5];
#pragma unroll
        for (int o = 0; o < 5; ++o) {
            float a = l2_b[o] + y1[o];
#pragma unroll
            for (int k = 0; k < 5; ++k) a = fmaf(y1[k], l2_w[o * 5 + k], a);
            y2[o] = elu1(a);
        }
        float y3[5];
#pragma unroll
        for (int o = 0; o < 5; ++o) {
            float a = l3_b[o] + y2[o];
#pragma unroll
            for (int k = 0; k < 5; ++k) a = fmaf(y2[k], l3_w[o * 5 + k], a);
            y3[o] = elu1(a);
        }
#pragma unroll
        for (int k = 0; k < 5; ++k) ymacc[k] = fmaf(y3[k], msk[j], ymacc[k]);
    }
    float ym[5];
#pragma unroll
    for (int k = 0; k < 5; ++k) ym[k] = gsum(ymacc[k]) * (1.f / R);

    // ---- phase C: fc1/fc2/fc3 per read, atomic max per read ----
    float pre2[5];
#pragma unroll
    for (int o = 0; o < 5; ++o) {
        float a = fc1_b[o];
#pragma unroll
        for (int k = 0; k < 5; ++k) a = fmaf(ym[k], fc1_w[o * 20 + k], a);
#pragma unroll
        for (int k = 0; k < 4; ++k) a = fmaf(bm[k], fc1_w[o * 20 + 5 + k], a);
        pre2[o] = a;
    }
#pragma unroll
    for (int j = 0; j < JMAX; ++j) {
        float h1[5];
#pragma unroll
        for (int o = 0; o < 5; ++o) {
            float a = fmaf(rdot[j], fc1_w[o * 20 + 9], pre2[o]);
#pragma unroll
            for (int k = 0; k < F; ++k) a = fmaf(f[j][k], fc1_w[o * 20 + 10 + k], a);
            h1[o] = elu1(a);
        }
        float h2[5];
#pragma unroll
        for (int o = 0; o < 5; ++o) {
            float a = fc2_b[o] + h1[o];
#pragma unroll
            for (int k = 0; k < 5; ++k) a = fmaf(h1[k], fc2_w[o * 5 + k], a);
            h2[o] = elu1(a);
        }
        // raw fc3 accumulator: sigmoid(5*elu(.)) monotone -> max commutes
        float a = fc3_b[0];
#pragma unroll
        for (int k = 0; k < 5; ++k) a = fmaf(h2[k], fc3_w[k], a);

        const int r = l + K * j;
        if (r < R) atomicMax(&wsmax[b * R + r], fkey(a));
    }
}

__global__ void alt_pred_k2(const unsigned int* __restrict__ wsmax,
                            float* __restrict__ out)
{
    const int i = blockIdx.x * blockDim.x + threadIdx.x;
    if (i < B * R) {
        const unsigned int key = wsmax[i];
        const unsigned int bits = (key & 0x80000000u) ? (key & 0x7FFFFFFFu) : ~key;
        const float acc = __uint_as_float(bits);
        const float h = 5.f * (acc > 0.f ? acc : (__expf(acc) - 1.f));
        out[i] = 1.f / (1.f + __expf(-h));
    }
}

extern "C" void kernel_launch(void* const* d_in, const int* in_sizes, int n_in,
                              void* d_out, int out_size, void* d_ws, size_t ws_size,
                              hipStream_t stream) {
    const float* x     = (const float*)d_in[0];
    const float* l1_w  = (const float*)d_in[1];
    const float* l1_b  = (const float*)d_in[2];
    const float* l2_w  = (const float*)d_in[3];
    const float* l2_b  = (const float*)d_in[4];
    const float* l3_w  = (const float*)d_in[5];
    const float* l3_b  = (const float*)d_in[6];
    const float* fc1_w = (const float*)d_in[7];
    const float* fc1_b = (const float*)d_in[8];
    const float* fc2_w = (const float*)d_in[9];
    const float* fc2_b = (const float*)d_in[10];
    const float* fc3_w = (const float*)d_in[11];
    const float* fc3_b = (const float*)d_in[12];

    unsigned int* wsmax = (unsigned int*)d_ws;
    hipMemsetAsync(d_ws, 0, (size_t)B * R * sizeof(unsigned int), stream);

    alt_pred_k1<<<NBLK, 256, 0, stream>>>(
        x, l1_w, l1_b, l2_w, l2_b, l3_w, l3_b,
        fc1_w, fc1_b, fc2_w, fc2_b, fc3_w, fc3_b, wsmax);

    alt_pred_k2<<<(B * R + 255) / 256, 256, 0, stream>>>(wsmax, (float*)d_out);
}

// Round 7
// 49.198 us; speedup vs baseline: 1.7949x; 1.7949x over previous
//
#include <hip/hip_runtime.h>
#include <math.h>

#define B 64
#define S 300
#define R 100
#define F 10
#define RF (R * F)
#define NTILE (B * S)          // 19200 tiles
#define TPWAVE 4               // 4 consecutive tiles per wave (2 v4-pairs); 4 | 300
#define NWAVE (NTILE / TPWAVE) // 4800 waves
#define NBLK (NWAVE / 4)       // 1200 blocks of 4 waves -> single balanced fill

typedef float v4 __attribute__((ext_vector_type(4)));

__device__ __forceinline__ v4 splat4(float s) { v4 r; r.x = s; r.y = s; r.z = s; r.w = s; return r; }
__device__ __forceinline__ v4 hsplat(float a, float b) { v4 r; r.x = a; r.y = a; r.z = b; r.w = b; return r; }
__device__ __forceinline__ v4 fma4(v4 a, float b, v4 c) {
    return __builtin_elementwise_fma(a, splat4(b), c);
}
__device__ __forceinline__ v4 fma4v(v4 a, v4 b, v4 c) {
    return __builtin_elementwise_fma(a, b, c);
}
__device__ __forceinline__ v4 vmax4(v4 a, v4 b) { return __builtin_elementwise_max(a, b); }
// elu(x) = max(x, exp(min(x,0)) - 1)
__device__ __forceinline__ v4 elu4(v4 x) {
    v4 xm = __builtin_elementwise_min(x, splat4(0.f));
    v4 e;
    e.x = __expf(xm.x); e.y = __expf(xm.y); e.z = __expf(xm.z); e.w = __expf(xm.w);
    return __builtin_elementwise_max(x, e - splat4(1.f));
}

// one DPP-shifted add step; out-of-row lanes contribute 0
template <int CTRL>
__device__ __forceinline__ float dppadd(float v) {
    int t = __builtin_amdgcn_update_dpp(0, __float_as_int(v), CTRL, 0xF, 0xF, true);
    return v + __int_as_float(t);
}
// full-wave64 sum -> uniform (row_shr 1/2/4/8, row_bcast 15/31, readlane 63)
__device__ __forceinline__ float wsum_dpp(float v) {
    v = dppadd<0x111>(v);
    v = dppadd<0x112>(v);
    v = dppadd<0x114>(v);
    v = dppadd<0x118>(v);
    v = dppadd<0x142>(v);
    v = dppadd<0x143>(v);
    return __uint_as_float(__builtin_amdgcn_readlane(__float_as_uint(v), 63));
}
__device__ __forceinline__ float rdlane0(float v) {
    return __uint_as_float(__builtin_amdgcn_readlane(__float_as_uint(v), 0));
}
__device__ __forceinline__ unsigned int fkey(float f) {
    unsigned int bits = __float_as_uint(f);
    return (bits & 0x80000000u) ? ~bits : (bits | 0x80000000u);
}

// compute one pair of tiles (xA, xA+RF); returns raw fc3 accumulator v4
__device__ __forceinline__ v4 pair_compute(
    const float* __restrict__ xA, int lane, bool a2, int r2,
    const float* __restrict__ l1_w, const float* __restrict__ l1_b,
    const float* __restrict__ l2_w, const float* __restrict__ l2_b,
    const float* __restrict__ l3_w, const float* __restrict__ l3_b,
    const float* __restrict__ fc1_w, const float* __restrict__ fc1_b,
    const float* __restrict__ fc2_w, const float* __restrict__ fc2_b,
    const float* __restrict__ fc3_w, const float* __restrict__ fc3_b)
{
    const float* xB = xA + RF;

    // ---- load 2 tiles x 2 reads, packed as (A.r1, A.r2, B.r1, B.r2) ----
    v4 f[F];
    {
        const float2* pA1 = (const float2*)(xA + lane * F);
        const float2* pA2 = (const float2*)(xA + r2 * F);
        const float2* pB1 = (const float2*)(xB + lane * F);
        const float2* pB2 = (const float2*)(xB + r2 * F);
#pragma unroll
        for (int i = 0; i < F; i += 2) {
            float2 a1 = pA1[i >> 1], a2v = pA2[i >> 1];
            float2 b1 = pB1[i >> 1], b2v = pB2[i >> 1];
            f[i].x = a1.x;     f[i].y = a2v.x; f[i].z = b1.x;     f[i].w = b2v.x;
            f[i + 1].x = a1.y; f[i + 1].y = a2v.y; f[i + 1].z = b1.y; f[i + 1].w = b2v.y;
        }
    }

    // ---- read-0 feats per tile -> uniform ----
    float x0A[4], x0B[4];
#pragma unroll
    for (int k = 0; k < 4; ++k) {
        x0A[k] = rdlane0(f[k].x);
        x0B[k] = rdlane0(f[k].z);
    }
    v4 rdot = f[3] * hsplat(x0A[3], x0B[3]);
    rdot = fma4v(f[2], hsplat(x0A[2], x0B[2]), rdot);
    rdot = fma4v(f[1], hsplat(x0A[1], x0B[1]), rdot);
    rdot = fma4v(f[0], hsplat(x0A[0], x0B[0]), rdot);

    // ---- mean of feat[0:4] over 100 reads, per tile ----
    float bmA[4], bmB[4];
#pragma unroll
    for (int k = 0; k < 4; ++k) {
        float locA = f[k].x + (a2 ? f[k].y : 0.f);
        float locB = f[k].z + (a2 ? f[k].w : 0.f);
        bmA[k] = wsum_dpp(locA) * (1.f / R);
        bmB[k] = wsum_dpp(locB) * (1.f / R);
    }

    // ---- l1: [bm(4), rdot, f(10)] ----
    v4 y1[5];
#pragma unroll
    for (int o = 0; o < 5; ++o) {
        float pA = l1_b[o], pB = l1_b[o];
#pragma unroll
        for (int k = 0; k < 4; ++k) {
            pA = fmaf(bmA[k], l1_w[o * 15 + k], pA);
            pB = fmaf(bmB[k], l1_w[o * 15 + k], pB);
        }
        v4 acc = hsplat(pA, pB);
        acc = fma4(rdot, l1_w[o * 15 + 4], acc);
#pragma unroll
        for (int k = 0; k < F; ++k) acc = fma4(f[k], l1_w[o * 15 + 5 + k], acc);
        y1[o] = elu4(acc);
    }
    // ---- l2 (+residual) ----
    v4 y2[5];
#pragma unroll
    for (int o = 0; o < 5; ++o) {
        v4 acc = splat4(l2_b[o]) + y1[o];
#pragma unroll
        for (int k = 0; k < 5; ++k) acc = fma4(y1[k], l2_w[o * 5 + k], acc);
        y2[o] = elu4(acc);
    }
    // ---- l3 (+residual) ----
    v4 y3[5];
#pragma unroll
    for (int o = 0; o < 5; ++o) {
        v4 acc = splat4(l3_b[o]) + y2[o];
#pragma unroll
        for (int k = 0; k < 5; ++k) acc = fma4(y2[k], l3_w[o * 5 + k], acc);
        y3[o] = elu4(acc);
    }

    // ---- mean of y3 over 100 reads, per tile ----
    float ymA[5], ymB[5];
#pragma unroll
    for (int k = 0; k < 5; ++k) {
        float locA = y3[k].x + (a2 ? y3[k].y : 0.f);
        float locB = y3[k].z + (a2 ? y3[k].w : 0.f);
        ymA[k] = wsum_dpp(locA) * (1.f / R);
        ymB[k] = wsum_dpp(locB) * (1.f / R);
    }

    // ---- fc1: [ym(5), bm(4), rdot, f(10)] ----
    v4 h1[5];
#pragma unroll
    for (int o = 0; o < 5; ++o) {
        float pA = fc1_b[o], pB = fc1_b[o];
#pragma unroll
        for (int k = 0; k < 5; ++k) {
            pA = fmaf(ymA[k], fc1_w[o * 20 + k], pA);
            pB = fmaf(ymB[k], fc1_w[o * 20 + k], pB);
        }
#pragma unroll
        for (int k = 0; k < 4; ++k) {
            pA = fmaf(bmA[k], fc1_w[o * 20 + 5 + k], pA);
            pB = fmaf(bmB[k], fc1_w[o * 20 + 5 + k], pB);
        }
        v4 acc = hsplat(pA, pB);
        acc = fma4(rdot, fc1_w[o * 20 + 9], acc);
#pragma unroll
        for (int k = 0; k < F; ++k) acc = fma4(f[k], fc1_w[o * 20 + 10 + k], acc);
        h1[o] = elu4(acc);
    }
    // ---- fc2 (+residual) ----
    v4 h2[5];
#pragma unroll
    for (int o = 0; o < 5; ++o) {
        v4 acc = splat4(fc2_b[o]) + h1[o];
#pragma unroll
        for (int k = 0; k < 5; ++k) acc = fma4(h1[k], fc2_w[o * 5 + k], acc);
        h2[o] = elu4(acc);
    }
    // ---- fc3 raw accumulator (sigmoid(5*elu(.)) monotone -> max commutes) ----
    v4 hacc = splat4(fc3_b[0]);
#pragma unroll
    for (int k = 0; k < 5; ++k) hacc = fma4(h2[k], fc3_w[k], hacc);
    return hacc;
}

__global__ __launch_bounds__(256) void alt_pred_k1(
    const float* __restrict__ x,
    const float* __restrict__ l1_w, const float* __restrict__ l1_b,
    const float* __restrict__ l2_w, const float* __restrict__ l2_b,
    const float* __restrict__ l3_w, const float* __restrict__ l3_b,
    const float* __restrict__ fc1_w, const float* __restrict__ fc1_b,
    const float* __restrict__ fc2_w, const float* __restrict__ fc2_b,
    const float* __restrict__ fc3_w, const float* __restrict__ fc3_b,
    unsigned int* __restrict__ wsmax)
{
    const int tid = threadIdx.x;
    const int wv = tid >> 6;
    const int lane = tid & 63;
    const int gw = blockIdx.x * 4 + wv;     // global wave id
    const int t0 = gw * TPWAVE;             // 4 consecutive tiles, same b (4|300)
    const int b = t0 / S;

    const bool a2 = (lane < R - 64);
    const int r2 = a2 ? (lane + 64) : (R - 1);

    v4 m = pair_compute(x + (size_t)t0 * RF, lane, a2, r2,
                        l1_w, l1_b, l2_w, l2_b, l3_w, l3_b,
                        fc1_w, fc1_b, fc2_w, fc2_b, fc3_w, fc3_b);
    m = vmax4(m, pair_compute(x + (size_t)(t0 + 2) * RF, lane, a2, r2,
                              l1_w, l1_b, l2_w, l2_b, l3_w, l3_b,
                              fc1_w, fc1_b, fc2_w, fc2_b, fc3_w, fc3_b));

    // max over the wave's 4 tiles, then one atomic per read slot
    const float m1 = fmaxf(m.x, m.z);   // read r1 = lane
    const float m2 = fmaxf(m.y, m.w);   // read r2 = lane+64
    atomicMax(&wsmax[b * R + lane], fkey(m1));
    if (a2) atomicMax(&wsmax[b * R + lane + 64], fkey(m2));
}

__global__ void alt_pred_k2(const unsigned int* __restrict__ wsmax,
                            float* __restrict__ out)
{
    const int i = blockIdx.x * blockDim.x + threadIdx.x;
    if (i < B * R) {
        const unsigned int key = wsmax[i];
        const unsigned int bits = (key & 0x80000000u) ? (key & 0x7FFFFFFFu) : ~key;
        const float acc = __uint_as_float(bits);
        const float h = 5.f * (acc > 0.f ? acc : (__expf(acc) - 1.f));
        out[i] = 1.f / (1.f + __expf(-h));
    }
}

extern "C" void kernel_launch(void* const* d_in, const int* in_sizes, int n_in,
                              void* d_out, int out_size, void* d_ws, size_t ws_size,
                              hipStream_t stream) {
    const float* x     = (const float*)d_in[0];
    const float* l1_w  = (const float*)d_in[1];
    const float* l1_b  = (const float*)d_in[2];
    const float* l2_w  = (const float*)d_in[3];
    const float* l2_b  = (const float*)d_in[4];
    const float* l3_w  = (const float*)d_in[5];
    const float* l3_b  = (const float*)d_in[6];
    const float* fc1_w = (const float*)d_in[7];
    const float* fc1_b = (const float*)d_in[8];
    const float* fc2_w = (const float*)d_in[9];
    const float* fc2_b = (const float*)d_in[10];
    const float* fc3_w = (const float*)d_in[11];
    const float* fc3_b = (const float*)d_in[12];

    unsigned int* wsmax = (unsigned int*)d_ws;
    hipMemsetAsync(d_ws, 0, (size_t)B * R * sizeof(unsigned int), stream);

    alt_pred_k1<<<NBLK, 256, 0, stream>>>(
        x, l1_w, l1_b, l2_w, l2_b, l3_w, l3_b,
        fc1_w, fc1_b, fc2_w, fc2_b, fc3_w, fc3_b, wsmax);

    alt_pred_k2<<<(B * R + 255) / 256, 256, 0, stream>>>(wsmax, (float*)d_out);
}

// Round 8
// 48.500 us; speedup vs baseline: 1.8207x; 1.0144x over previous
//
#include <hip/hip_runtime.h>
#include <math.h>

#define B 64
#define S 300
#define R 100
#define F 10
#define RF (R * F)
#define NTILE (B * S)          // 19200 tiles
#define NWAVE (NTILE / 2)      // 9600 waves, one 2-tile pair per wave
#define NBLK (NWAVE / 2)       // 4800 blocks x 128 threads (2 waves)

typedef float v2f __attribute__((ext_vector_type(2)));

#define LOG2E 1.44269504088896340736f

__device__ __forceinline__ v2f splat2(float s) { v2f r; r.x = s; r.y = s; return r; }
__device__ __forceinline__ v2f fma2s(v2f a, float b, v2f c) {
    return __builtin_elementwise_fma(a, splat2(b), c);
}
__device__ __forceinline__ v2f fma2v(v2f a, v2f b, v2f c) {
    return __builtin_elementwise_fma(a, b, c);
}
// elu(x) = max(x, exp2(min(x,0)*log2e) - 1)
__device__ __forceinline__ v2f elu2(v2f x) {
    v2f t = __builtin_elementwise_min(x, splat2(0.f)) * splat2(LOG2E);
    v2f e; e.x = exp2f(t.x); e.y = exp2f(t.y);
    return __builtin_elementwise_max(x, e - splat2(1.f));
}

// one DPP-shifted add step on a float2 (two quantities per tree)
template <int CTRL>
__device__ __forceinline__ v2f dppadd2(v2f v) {
    int tx = __builtin_amdgcn_update_dpp(0, __float_as_int(v.x), CTRL, 0xF, 0xF, true);
    int ty = __builtin_amdgcn_update_dpp(0, __float_as_int(v.y), CTRL, 0xF, 0xF, true);
    v2f t; t.x = __int_as_float(tx); t.y = __int_as_float(ty);
    return v + t;   // v_pk_add_f32
}
// dual 64-lane sum * 1/R -> two uniform scalars
__device__ __forceinline__ void wmean2(v2f v, float& a, float& b) {
    v = dppadd2<0x111>(v);
    v = dppadd2<0x112>(v);
    v = dppadd2<0x114>(v);
    v = dppadd2<0x118>(v);
    v = dppadd2<0x142>(v);
    v = dppadd2<0x143>(v);
    v = v * splat2(1.f / R);
    a = __uint_as_float(__builtin_amdgcn_readlane(__float_as_uint(v.x), 63));
    b = __uint_as_float(__builtin_amdgcn_readlane(__float_as_uint(v.y), 63));
}
__device__ __forceinline__ unsigned int fkey(float f) {
    unsigned int bits = __float_as_uint(f);
    return (bits & 0x80000000u) ? ~bits : (bits | 0x80000000u);
}

__global__ __launch_bounds__(128) void alt_pred_k1(
    const float* __restrict__ x,
    const float* __restrict__ l1_w, const float* __restrict__ l1_b,
    const float* __restrict__ l2_w, const float* __restrict__ l2_b,
    const float* __restrict__ l3_w, const float* __restrict__ l3_b,
    const float* __restrict__ fc1_w, const float* __restrict__ fc1_b,
    const float* __restrict__ fc2_w, const float* __restrict__ fc2_b,
    const float* __restrict__ fc3_w, const float* __restrict__ fc3_b,
    unsigned int* __restrict__ wsmax)
{
    const int tid = threadIdx.x;
    const int lane = tid & 63;
    // force wave-uniform tile index into SGPRs (enables s_load of x0 / addrs)
    const int t0 = __builtin_amdgcn_readfirstlane((blockIdx.x * 2 + (tid >> 6)) * 2);
    const int b = t0 / S;
    const float* xA = x + (size_t)t0 * RF;
    const float* xB = xA + RF;

    const bool a2 = (lane < R - 64);
    const int r2 = a2 ? (lane + 64) : (R - 1);
    const v2f msk2 = splat2(a2 ? 1.f : 0.f);

    // ---- read-0 features: wave-uniform scalar loads (s_load, off VALU) ----
    float x0A[4], x0B[4];
#pragma unroll
    for (int k = 0; k < 4; ++k) { x0A[k] = xA[k]; x0B[k] = xB[k]; }

    // ---- vector loads: lo = (A.r1, B.r1), hi = (A.r2, B.r2) per feature ----
    v2f f_lo[F], f_hi[F];
    {
        const float2* pA1 = (const float2*)(xA + lane * F);
        const float2* pA2 = (const float2*)(xA + r2 * F);
        const float2* pB1 = (const float2*)(xB + lane * F);
        const float2* pB2 = (const float2*)(xB + r2 * F);
#pragma unroll
        for (int i = 0; i < 5; ++i) {
            float2 a1 = pA1[i], b1 = pB1[i], a2v = pA2[i], b2v = pB2[i];
            f_lo[2 * i].x = a1.x;     f_lo[2 * i].y = b1.x;
            f_lo[2 * i + 1].x = a1.y; f_lo[2 * i + 1].y = b1.y;
            f_hi[2 * i].x = a2v.x;    f_hi[2 * i].y = b2v.x;
            f_hi[2 * i + 1].x = a2v.y; f_hi[2 * i + 1].y = b2v.y;
        }
    }

    // ---- rdot = dot(f[0:4], read0[0:4]) per slot ----
    v2f x0v[4];
#pragma unroll
    for (int k = 0; k < 4; ++k) { x0v[k].x = x0A[k]; x0v[k].y = x0B[k]; }
    v2f rdot_lo = f_lo[3] * x0v[3];
    v2f rdot_hi = f_hi[3] * x0v[3];
#pragma unroll
    for (int k = 2; k >= 0; --k) {
        rdot_lo = fma2v(f_lo[k], x0v[k], rdot_lo);
        rdot_hi = fma2v(f_hi[k], x0v[k], rdot_hi);
    }

    // ---- bm: mean of feat[0:4] over 100 reads, both tiles per tree ----
    float bmA[4], bmB[4];
#pragma unroll
    for (int k = 0; k < 4; ++k) {
        v2f loc = fma2v(f_hi[k], msk2, f_lo[k]);   // exclude dup r2 slots
        wmean2(loc, bmA[k], bmB[k]);
    }

    // ---- l1: [bm(4), rdot, f(10)] ----
    v2f y1_lo[5], y1_hi[5];
#pragma unroll
    for (int o = 0; o < 5; ++o) {
        float pA = l1_b[o], pB = l1_b[o];
#pragma unroll
        for (int k = 0; k < 4; ++k) {
            pA = fmaf(bmA[k], l1_w[o * 15 + k], pA);
            pB = fmaf(bmB[k], l1_w[o * 15 + k], pB);
        }
        v2f pre; pre.x = pA; pre.y = pB;
        v2f alo = fma2s(rdot_lo, l1_w[o * 15 + 4], pre);
        v2f ahi = fma2s(rdot_hi, l1_w[o * 15 + 4], pre);
#pragma unroll
        for (int k = 0; k < F; ++k) {
            alo = fma2s(f_lo[k], l1_w[o * 15 + 5 + k], alo);
            ahi = fma2s(f_hi[k], l1_w[o * 15 + 5 + k], ahi);
        }
        y1_lo[o] = elu2(alo); y1_hi[o] = elu2(ahi);
    }
    // ---- l2 (+residual) ----
    v2f y2_lo[5], y2_hi[5];
#pragma unroll
    for (int o = 0; o < 5; ++o) {
        v2f alo = y1_lo[o] + splat2(l2_b[o]);
        v2f ahi = y1_hi[o] + splat2(l2_b[o]);
#pragma unroll
        for (int k = 0; k < 5; ++k) {
            alo = fma2s(y1_lo[k], l2_w[o * 5 + k], alo);
            ahi = fma2s(y1_hi[k], l2_w[o * 5 + k], ahi);
        }
        y2_lo[o] = elu2(alo); y2_hi[o] = elu2(ahi);
    }
    // ---- l3 (+residual) ----
    v2f y3_lo[5], y3_hi[5];
#pragma unroll
    for (int o = 0; o < 5; ++o) {
        v2f alo = y2_lo[o] + splat2(l3_b[o]);
        v2f ahi = y2_hi[o] + splat2(l3_b[o]);
#pragma unroll
        for (int k = 0; k < 5; ++k) {
            alo = fma2s(y2_lo[k], l3_w[o * 5 + k], alo);
            ahi = fma2s(y2_hi[k], l3_w[o * 5 + k], ahi);
        }
        y3_lo[o] = elu2(alo); y3_hi[o] = elu2(ahi);
    }

    // ---- ym: mean of y3 over 100 reads, both tiles per tree ----
    float ymA[5], ymB[5];
#pragma unroll
    for (int k = 0; k < 5; ++k) {
        v2f loc = fma2v(y3_hi[k], msk2, y3_lo[k]);
        wmean2(loc, ymA[k], ymB[k]);
    }

    // ---- fc1: [ym(5), bm(4), rdot, f(10)] ----
    v2f h1_lo[5], h1_hi[5];
#pragma unroll
    for (int o = 0; o < 5; ++o) {
        float pA = fc1_b[o], pB = fc1_b[o];
#pragma unroll
        for (int k = 0; k < 5; ++k) {
            pA = fmaf(ymA[k], fc1_w[o * 20 + k], pA);
            pB = fmaf(ymB[k], fc1_w[o * 20 + k], pB);
        }
#pragma unroll
        for (int k = 0; k < 4; ++k) {
            pA = fmaf(bmA[k], fc1_w[o * 20 + 5 + k], pA);
            pB = fmaf(bmB[k], fc1_w[o * 20 + 5 + k], pB);
        }
        v2f pre; pre.x = pA; pre.y = pB;
        v2f alo = fma2s(rdot_lo, fc1_w[o * 20 + 9], pre);
        v2f ahi = fma2s(rdot_hi, fc1_w[o * 20 + 9], pre);
#pragma unroll
        for (int k = 0; k < F; ++k) {
            alo = fma2s(f_lo[k], fc1_w[o * 20 + 10 + k], alo);
            ahi = fma2s(f_hi[k], fc1_w[o * 20 + 10 + k], ahi);
        }
        h1_lo[o] = elu2(alo); h1_hi[o] = elu2(ahi);
    }
    // ---- fc2 (+residual) ----
    v2f h2_lo[5], h2_hi[5];
#pragma unroll
    for (int o = 0; o < 5; ++o) {
        v2f alo = h1_lo[o] + splat2(fc2_b[o]);
        v2f ahi = h1_hi[o] + splat2(fc2_b[o]);
#pragma unroll
        for (int k = 0; k < 5; ++k) {
            alo = fma2s(h1_lo[k], fc2_w[o * 5 + k], alo);
            ahi = fma2s(h1_hi[k], fc2_w[o * 5 + k], ahi);
        }
        h2_lo[o] = elu2(alo); h2_hi[o] = elu2(ahi);
    }
    // ---- fc3 raw accumulator (sigmoid(5*elu(.)) monotone -> max commutes) ----
    v2f hacc_lo = splat2(fc3_b[0]);
    v2f hacc_hi = splat2(fc3_b[0]);
#pragma unroll
    for (int k = 0; k < 5; ++k) {
        hacc_lo = fma2s(h2_lo[k], fc3_w[k], hacc_lo);
        hacc_hi = fma2s(h2_hi[k], fc3_w[k], hacc_hi);
    }

    // pair-max over the wave's 2 tiles, one atomic per read slot
    const float m1 = fmaxf(hacc_lo.x, hacc_lo.y);   // read r1 = lane
    const float m2 = fmaxf(hacc_hi.x, hacc_hi.y);   // read r2 = lane+64
    atomicMax(&wsmax[b * R + lane], fkey(m1));
    if (a2) atomicMax(&wsmax[b * R + lane + 64], fkey(m2));
}

__global__ void alt_pred_k2(const unsigned int* __restrict__ wsmax,
                            float* __restrict__ out)
{
    const int i = blockIdx.x * blockDim.x + threadIdx.x;
    if (i < B * R) {
        const unsigned int key = wsmax[i];
        const unsigned int bits = (key & 0x80000000u) ? (key & 0x7FFFFFFFu) : ~key;
        const float acc = __uint_as_float(bits);
        const float h = 5.f * (acc > 0.f ? acc : (__expf(acc) - 1.f));
        out[i] = 1.f / (1.f + __expf(-h));
    }
}

extern "C" void kernel_launch(void* const* d_in, const int* in_sizes, int n_in,
                              void* d_out, int out_size, void* d_ws, size_t ws_size,
                              hipStream_t stream) {
    const float* x     = (const float*)d_in[0];
    const float* l1_w  = (const float*)d_in[1];
    const float* l1_b  = (const float*)d_in[2];
    const float* l2_w  = (const float*)d_in[3];
    const float* l2_b  = (const float*)d_in[4];
    const float* l3_w  = (const float*)d_in[5];
    const float* l3_b  = (const float*)d_in[6];
    const float* fc1_w = (const float*)d_in[7];
    const float* fc1_b = (const float*)d_in[8];
    const float* fc2_w = (const float*)d_in[9];
    const float* fc2_b = (const float*)d_in[10];
    const float* fc3_w = (const float*)d_in[11];
    const float* fc3_b = (const float*)d_in[12];

    unsigned int* wsmax = (unsigned int*)d_ws;
    hipMemsetAsync(d_ws, 0, (size_t)B * R * sizeof(unsigned int), stream);

    alt_pred_k1<<<NBLK, 128, 0, stream>>>(
        x, l1_w, l1_b, l2_w, l2_b, l3_w, l3_b,
        fc1_w, fc1_b, fc2_w, fc2_b, fc3_w, fc3_b, wsmax);

    alt_pred_k2<<<(B * R + 255) / 256, 256, 0, stream>>>(wsmax, (float*)d_out);
}

// Round 9
// 41.072 us; speedup vs baseline: 2.1500x; 1.1809x over previous
//
#include <hip/hip_runtime.h>
#include <math.h>

#define B 64
#define S 300
#define R 100
#define F 10
#define RF (R * F)
#define NTILE (B * S)          // 19200 tiles
#define NWAVE (NTILE / 2)      // 9600 waves, one 2-tile pair per wave
#define NBLK (NWAVE / 4)       // 2400 blocks x 256 threads (4 waves)

typedef float v4 __attribute__((ext_vector_type(4)));

__device__ __forceinline__ v4 splat4(float s) { v4 r; r.x = s; r.y = s; r.z = s; r.w = s; return r; }
__device__ __forceinline__ v4 hsplat(float a, float b) { v4 r; r.x = a; r.y = a; r.z = b; r.w = b; return r; }
__device__ __forceinline__ v4 fma4(v4 a, float b, v4 c) {
    return __builtin_elementwise_fma(a, splat4(b), c);
}
__device__ __forceinline__ v4 fma4v(v4 a, v4 b, v4 c) {
    return __builtin_elementwise_fma(a, b, c);
}
// elu(x) = max(x, exp(min(x,0)) - 1)
__device__ __forceinline__ v4 elu4(v4 x) {
    v4 xm = __builtin_elementwise_min(x, splat4(0.f));
    v4 e;
    e.x = __expf(xm.x); e.y = __expf(xm.y); e.z = __expf(xm.z); e.w = __expf(xm.w);
    return __builtin_elementwise_max(x, e - splat4(1.f));
}

// one DPP-shifted add step; out-of-row lanes contribute 0
template <int CTRL>
__device__ __forceinline__ float dppadd(float v) {
    int t = __builtin_amdgcn_update_dpp(0, __float_as_int(v), CTRL, 0xF, 0xF, true);
    return v + __int_as_float(t);
}
// full-wave64 sum -> uniform (row_shr 1/2/4/8, row_bcast 15/31, readlane 63)
__device__ __forceinline__ float wsum_dpp(float v) {
    v = dppadd<0x111>(v);
    v = dppadd<0x112>(v);
    v = dppadd<0x114>(v);
    v = dppadd<0x118>(v);
    v = dppadd<0x142>(v);
    v = dppadd<0x143>(v);
    return __uint_as_float(__builtin_amdgcn_readlane(__float_as_uint(v), 63));
}
__device__ __forceinline__ unsigned int fkey(float f) {
    unsigned int bits = __float_as_uint(f);
    return (bits & 0x80000000u) ? ~bits : (bits | 0x80000000u);
}

__global__ __launch_bounds__(256) void alt_pred_k1(
    const float* __restrict__ x,
    const float* __restrict__ l1_w, const float* __restrict__ l1_b,
    const float* __restrict__ l2_w, const float* __restrict__ l2_b,
    const float* __restrict__ l3_w, const float* __restrict__ l3_b,
    const float* __restrict__ fc1_w, const float* __restrict__ fc1_b,
    const float* __restrict__ fc2_w, const float* __restrict__ fc2_b,
    const float* __restrict__ fc3_w, const float* __restrict__ fc3_b,
    unsigned int* __restrict__ wsmax)
{
    const int tid = threadIdx.x;
    const int lane = tid & 63;
    // wave-uniform tile pair index pinned to SGPR (enables s_load of x0)
    const int t0 = __builtin_amdgcn_readfirstlane((blockIdx.x * 4 + (tid >> 6)) * 2);
    const int b = t0 / S;
    const float* xA = x + (size_t)t0 * RF;
    const float* xB = xA + RF;

    const bool a2 = (lane < R - 64);
    const int r2 = a2 ? (lane + 64) : (R - 1);

    // ---- read-0 features: wave-uniform scalar loads (off the VALU path) ----
    float x0A[4], x0B[4];
#pragma unroll
    for (int k = 0; k < 4; ++k) { x0A[k] = xA[k]; x0B[k] = xB[k]; }

    // ---- load 2 tiles x 2 reads, packed as (A.r1, A.r2, B.r1, B.r2) ----
    v4 f[F];
    {
        const float2* pA1 = (const float2*)(xA + lane * F);
        const float2* pA2 = (const float2*)(xA + r2 * F);
        const float2* pB1 = (const float2*)(xB + lane * F);
        const float2* pB2 = (const float2*)(xB + r2 * F);
#pragma unroll
        for (int i = 0; i < F; i += 2) {
            float2 a1 = pA1[i >> 1], a2v = pA2[i >> 1];
            float2 b1 = pB1[i >> 1], b2v = pB2[i >> 1];
            f[i].x = a1.x;     f[i].y = a2v.x; f[i].z = b1.x;     f[i].w = b2v.x;
            f[i + 1].x = a1.y; f[i + 1].y = a2v.y; f[i + 1].z = b1.y; f[i + 1].w = b2v.y;
        }
    }

    // ---- rdot = dot(f[0:4], read0[0:4]) per slot ----
    v4 rdot = f[3] * hsplat(x0A[3], x0B[3]);
    rdot = fma4v(f[2], hsplat(x0A[2], x0B[2]), rdot);
    rdot = fma4v(f[1], hsplat(x0A[1], x0B[1]), rdot);
    rdot = fma4v(f[0], hsplat(x0A[0], x0B[0]), rdot);

    // ---- mean of feat[0:4] over 100 reads, per tile ----
    float bmA[4], bmB[4];
#pragma unroll
    for (int k = 0; k < 4; ++k) {
        float locA = f[k].x + (a2 ? f[k].y : 0.f);
        float locB = f[k].z + (a2 ? f[k].w : 0.f);
        bmA[k] = wsum_dpp(locA) * (1.f / R);
        bmB[k] = wsum_dpp(locB) * (1.f / R);
    }

    // ---- l1: [bm(4), rdot, f(10)] ----
    v4 y1[5];
#pragma unroll
    for (int o = 0; o < 5; ++o) {
        float pA = l1_b[o], pB = l1_b[o];
#pragma unroll
        for (int k = 0; k < 4; ++k) {
            pA = fmaf(bmA[k], l1_w[o * 15 + k], pA);
            pB = fmaf(bmB[k], l1_w[o * 15 + k], pB);
        }
        v4 acc = hsplat(pA, pB);
        acc = fma4(rdot, l1_w[o * 15 + 4], acc);
#pragma unroll
        for (int k = 0; k < F; ++k) acc = fma4(f[k], l1_w[o * 15 + 5 + k], acc);
        y1[o] = elu4(acc);
    }
    // ---- l2 (+residual) ----
    v4 y2[5];
#pragma unroll
    for (int o = 0; o < 5; ++o) {
        v4 acc = splat4(l2_b[o]) + y1[o];
#pragma unroll
        for (int k = 0; k < 5; ++k) acc = fma4(y1[k], l2_w[o * 5 + k], acc);
        y2[o] = elu4(acc);
    }
    // ---- l3 (+residual) ----
    v4 y3[5];
#pragma unroll
    for (int o = 0; o < 5; ++o) {
        v4 acc = splat4(l3_b[o]) + y2[o];
#pragma unroll
        for (int k = 0; k < 5; ++k) acc = fma4(y2[k], l3_w[o * 5 + k], acc);
        y3[o] = elu4(acc);
    }

    // ---- mean of y3 over 100 reads, per tile ----
    float ymA[5], ymB[5];
#pragma unroll
    for (int k = 0; k < 5; ++k) {
        float locA = y3[k].x + (a2 ? y3[k].y : 0.f);
        float locB = y3[k].z + (a2 ? y3[k].w : 0.f);
        ymA[k] = wsum_dpp(locA) * (1.f / R);
        ymB[k] = wsum_dpp(locB) * (1.f / R);
    }

    // ---- fc1: [ym(5), bm(4), rdot, f(10)] ----
    v4 h1[5];
#pragma unroll
    for (int o = 0; o < 5; ++o) {
        float pA = fc1_b[o], pB = fc1_b[o];
#pragma unroll
        for (int k = 0; k < 5; ++k) {
            pA = fmaf(ymA[k], fc1_w[o * 20 + k], pA);
            pB = fmaf(ymB[k], fc1_w[o * 20 + k], pB);
        }
#pragma unroll
        for (int k = 0; k < 4; ++k) {
            pA = fmaf(bmA[k], fc1_w[o * 20 + 5 + k], pA);
            pB = fmaf(bmB[k], fc1_w[o * 20 + 5 + k], pB);
        }
        v4 acc = hsplat(pA, pB);
        acc = fma4(rdot, fc1_w[o * 20 + 9], acc);
#pragma unroll
        for (int k = 0; k < F; ++k) acc = fma4(f[k], fc1_w[o * 20 + 10 + k], acc);
        h1[o] = elu4(acc);
    }
    // ---- fc2 (+residual) ----
    v4 h2[5];
#pragma unroll
    for (int o = 0; o < 5; ++o) {
        v4 acc = splat4(fc2_b[o]) + h1[o];
#pragma unroll
        for (int k = 0; k < 5; ++k) acc = fma4(h1[k], fc2_w[o * 5 + k], acc);
        h2[o] = elu4(acc);
    }
    // ---- fc3 raw accumulator (sigmoid(5*elu(.)) monotone -> max commutes) ----
    v4 hacc = splat4(fc3_b[0]);
#pragma unroll
    for (int k = 0; k < 5; ++k) hacc = fma4(h2[k], fc3_w[k], hacc);

    // pair-max over the wave's 2 tiles, one atomic per read slot
    const float m1 = fmaxf(hacc.x, hacc.z);   // read r1 = lane
    const float m2 = fmaxf(hacc.y, hacc.w);   // read r2 = lane+64
    atomicMax(&wsmax[b * R + lane], fkey(m1));
    if (a2) atomicMax(&wsmax[b * R + lane + 64], fkey(m2));
}

__global__ void alt_pred_k2(const unsigned int* __restrict__ wsmax,
                            float* __restrict__ out)
{
    const int i = blockIdx.x * blockDim.x + threadIdx.x;
    if (i < B * R) {
        const unsigned int key = wsmax[i];
        const unsigned int bits = (key & 0x80000000u) ? (key & 0x7FFFFFFFu) : ~key;
        const float acc = __uint_as_float(bits);
        const float h = 5.f * (acc > 0.f ? acc : (__expf(acc) - 1.f));
        out[i] = 1.f / (1.f + __expf(-h));
    }
}

extern "C" void kernel_launch(void* const* d_in, const int* in_sizes, int n_in,
                              void* d_out, int out_size, void* d_ws, size_t ws_size,
                              hipStream_t stream) {
    const float* x     = (const float*)d_in[0];
    const float* l1_w  = (const float*)d_in[1];
    const float* l1_b  = (const float*)d_in[2];
    const float* l2_w  = (const float*)d_in[3];
    const float* l2_b  = (const float*)d_in[4];
    const float* l3_w  = (const float*)d_in[5];
    const float* l3_b  = (const float*)d_in[6];
    const float* fc1_w = (const float*)d_in[7];
    const float* fc1_b = (const float*)d_in[8];
    const float* fc2_w = (const float*)d_in[9];
    const float* fc2_b = (const float*)d_in[10];
    const float* fc3_w = (const float*)d_in[11];
    const float* fc3_b = (const float*)d_in[12];

    unsigned int* wsmax = (unsigned int*)d_ws;
    hipMemsetAsync(d_ws, 0, (size_t)B * R * sizeof(unsigned int), stream);

    alt_pred_k1<<<NBLK, 256, 0, stream>>>(
        x, l1_w, l1_b, l2_w, l2_b, l3_w, l3_b,
        fc1_w, fc1_b, fc2_w, fc2_b, fc3_w, fc3_b, wsmax);

    alt_pred_k2<<<(B * R + 255) / 256, 256, 0, stream>>>(wsmax, (float*)d_out);
}